// Round 3
// baseline (909.984 us; speedup 1.0000x reference)
//
#include <hip/hip_runtime.h>
#include <hip/hip_bf16.h>

typedef float f32x4 __attribute__((ext_vector_type(4)));
typedef short short8 __attribute__((ext_vector_type(8)));

#define NTOT   65536
#define DDIM   256
#define KCODES 1024
#define BRR    128          // z rows per block
#define CT     128          // codes per tile
#define BD     64           // d per LDS chunk
#define IDXOFF 16777217     // 1 + NTOT*DDIM
#define MARGIN 0.05f

// ws layout (fp32 elems): [0] loss accum, [8] flag count (int), [1024..2048) wsq,
// [2048..2048+65536) flagged row list (int)

__device__ __forceinline__ unsigned short bf16_rne(float x) {
  unsigned u = __float_as_uint(x);
  return (unsigned short)((u + 0x7fff + ((u >> 16) & 1)) >> 16);
}

// ---------------- kernel 1: wsq[k] = ||w_k||^2 ----------------
__global__ __launch_bounds__(256) void wsq_kernel(const float* __restrict__ w,
                                                  float* __restrict__ wsq) {
  int k = blockIdx.x * 256 + threadIdx.x;
  if (k >= KCODES) return;
  const f32x4* wr = (const f32x4*)(w + (size_t)k * DDIM);
  float s = 0.f;
#pragma unroll 8
  for (int j = 0; j < DDIM / 4; ++j) {
    f32x4 v = wr[j];
    s += v[0] * v[0] + v[1] * v[1] + v[2] * v[2] + v[3] * v[3];
  }
  wsq[k] = s;
}

// stage a [128 rows][64 d] fp32 tile as hi/lo bf16 planes into swizzled LDS
__device__ __forceinline__ void stage_tile(const float* __restrict__ gsrc,
                                           short* hi_t, short* lo_t, int tid) {
#pragma unroll
  for (int it = 0; it < 8; ++it) {
    int flat4 = it * 256 + tid;   // 2048 f32x4 = 8192 elems
    int row = flat4 >> 4;
    int k = (flat4 & 15) * 4;
    f32x4 v = *(const f32x4*)(gsrc + (size_t)row * DDIM + k);
    unsigned h[4], l[4];
#pragma unroll
    for (int j = 0; j < 4; ++j) {
      unsigned short hb = bf16_rne(v[j]);
      float hf = __uint_as_float(((unsigned)hb) << 16);
      h[j] = hb;
      l[j] = bf16_rne(v[j] - hf);
    }
    int off = row * 128 + ((k * 2) ^ ((row & 7) << 4));
    *(int2*)((char*)hi_t + off) = make_int2((int)(h[0] | (h[1] << 16)), (int)(h[2] | (h[3] << 16)));
    *(int2*)((char*)lo_t + off) = make_int2((int)(l[0] | (l[1] << 16)), (int)(l[2] | (l[3] << 16)));
  }
}

__device__ __forceinline__ short8 frag_ld(const short* t, int row, int kbyte) {
  return *(const short8*)((const char*)t + row * 128 + (kbyte ^ ((row & 7) << 4)));
}

// ---------------- kernel 2: MFMA distances + argmin(+margin) + gather + loss ----------------
__global__ __launch_bounds__(256, 2) void vq_main(
    const float* __restrict__ z, const float* __restrict__ w,
    const float* __restrict__ wsq, float* __restrict__ loss_accum,
    int* __restrict__ cnt, int* __restrict__ list, float* __restrict__ out) {
  __shared__ __align__(16) short whi[CT * BD], wlo[CT * BD];
  __shared__ __align__(16) short zhi[BRR * BD], zlo[BRR * BD];
  __shared__ __align__(16) float wsq_l[KCODES];
  __shared__ int sidx[BRR];
  __shared__ int sflag[BRR];
  __shared__ float wsum[4];

  const int tid = threadIdx.x;
  const int lane = tid & 63, wid = tid >> 6;
  const int br = blockIdx.x * BRR;
  const int l15 = lane & 15, lg = lane >> 4;

  for (int i = tid; i < KCODES; i += 256) wsq_l[i] = wsq[i];

  float minv[2] = {3.4e38f, 3.4e38f}, min2[2] = {3.4e38f, 3.4e38f};
  int mini[2] = {0, 0};
  const int zr0 = wid * 32 + l15, zr1 = zr0 + 16;

  for (int ct = 0; ct < KCODES / CT; ++ct) {
    const int kb = ct * CT;
    f32x4 acc[8][2];
#pragma unroll
    for (int mi = 0; mi < 8; ++mi)
#pragma unroll
      for (int ni = 0; ni < 2; ++ni) acc[mi][ni] = (f32x4){0.f, 0.f, 0.f, 0.f};

    for (int dc = 0; dc < DDIM / BD; ++dc) {
      const int d0 = dc * BD;
      __syncthreads();
      stage_tile(w + (size_t)kb * DDIM + d0, whi, wlo, tid);
      stage_tile(z + (size_t)br * DDIM + d0, zhi, zlo, tid);
      __syncthreads();
#pragma unroll
      for (int ks = 0; ks < 2; ++ks) {
        const int kb2 = (ks * 32 + (lg << 3)) * 2;
        short8 bh0 = frag_ld(zhi, zr0, kb2), bl0 = frag_ld(zlo, zr0, kb2);
        short8 bh1 = frag_ld(zhi, zr1, kb2), bl1 = frag_ld(zlo, zr1, kb2);
#pragma unroll
        for (int mi = 0; mi < 8; ++mi) {
          const int wr = mi * 16 + l15;
          short8 ah = frag_ld(whi, wr, kb2), al = frag_ld(wlo, wr, kb2);
          acc[mi][0] = __builtin_amdgcn_mfma_f32_16x16x32_bf16(ah, bh0, acc[mi][0], 0, 0, 0);
          acc[mi][0] = __builtin_amdgcn_mfma_f32_16x16x32_bf16(ah, bl0, acc[mi][0], 0, 0, 0);
          acc[mi][0] = __builtin_amdgcn_mfma_f32_16x16x32_bf16(al, bh0, acc[mi][0], 0, 0, 0);
          acc[mi][1] = __builtin_amdgcn_mfma_f32_16x16x32_bf16(ah, bh1, acc[mi][1], 0, 0, 0);
          acc[mi][1] = __builtin_amdgcn_mfma_f32_16x16x32_bf16(ah, bl1, acc[mi][1], 0, 0, 0);
          acc[mi][1] = __builtin_amdgcn_mfma_f32_16x16x32_bf16(al, bh1, acc[mi][1], 0, 0, 0);
        }
      }
    }
    // epilogue: score = wsq - 2*dot; running (min, min2, idx); codes ascend per lane
#pragma unroll
    for (int ni = 0; ni < 2; ++ni)
#pragma unroll
      for (int mi = 0; mi < 8; ++mi)
#pragma unroll
        for (int rg = 0; rg < 4; ++rg) {
          int code = kb + mi * 16 + (lg << 2) + rg;
          float s = fmaf(-2.f, acc[mi][ni][rg], wsq_l[code]);
          if (s < minv[ni]) { min2[ni] = minv[ni]; minv[ni] = s; mini[ni] = code; }
          else if (s < min2[ni]) min2[ni] = s;
        }
  }

  // cross-lane merge over the 4 k-groups (xor 16, 32); ties -> margin 0 -> refine
#pragma unroll
  for (int ni = 0; ni < 2; ++ni) {
#pragma unroll
    for (int off = 16; off <= 32; off <<= 1) {
      float om = __shfl_xor(minv[ni], off);
      float om2 = __shfl_xor(min2[ni], off);
      int oi = __shfl_xor(mini[ni], off);
      if (om < minv[ni]) { min2[ni] = fminf(minv[ni], om2); minv[ni] = om; mini[ni] = oi; }
      else { min2[ni] = fminf(min2[ni], om); }
    }
  }
  if (lg == 0) {
#pragma unroll
    for (int ni = 0; ni < 2; ++ni) {
      int rl = wid * 32 + ni * 16 + l15;
      int grow = br + rl;
      int flg = (min2[ni] - minv[ni] < MARGIN) ? 1 : 0;
      sidx[rl] = mini[ni];
      sflag[rl] = flg;
      if (!flg) out[(size_t)IDXOFF + grow] = (float)mini[ni];
      else { int p = atomicAdd(cnt, 1); list[p] = grow; }
    }
  }
  __syncthreads();

  // gather z_q, write z_q_st = z + (z_q - z), accumulate loss (skip flagged rows)
  float lsum = 0.f;
  for (int r = 0; r < BRR; ++r) {
    if (!sflag[r]) {
      int idx = sidx[r];
      float qv = w[(size_t)idx * DDIM + tid];
      float zv = z[(size_t)(br + r) * DDIM + tid];
      float df = qv - zv;
      out[1 + (size_t)(br + r) * DDIM + tid] = zv + df;
      lsum = fmaf(df, df, lsum);
    }
  }
#pragma unroll
  for (int off = 32; off > 0; off >>= 1) lsum += __shfl_down(lsum, off, 64);
  if (lane == 0) wsum[wid] = lsum;
  __syncthreads();
  if (tid == 0) atomicAdd(loss_accum, wsum[0] + wsum[1] + wsum[2] + wsum[3]);
}

// ---------------- kernel 3: exact fp32 recompute for flagged rows ----------------
__global__ __launch_bounds__(256) void vq_refine(
    const float* __restrict__ z, const float* __restrict__ w,
    const float* __restrict__ wsq, float* __restrict__ loss_accum,
    const int* __restrict__ cnt, const int* __restrict__ list,
    float* __restrict__ out) {
  __shared__ __align__(16) float zrow[DDIM];
  __shared__ float rv[256];
  __shared__ int ri[256];
  const int tid = threadIdx.x;
  const int n = *cnt;
  for (int li = blockIdx.x; li < n; li += gridDim.x) {
    const int row = list[li];
    __syncthreads();
    zrow[tid] = z[(size_t)row * DDIM + tid];
    __syncthreads();
    float bv = 3.4e38f; int bi = 0;
#pragma unroll
    for (int c0 = 0; c0 < 4; ++c0) {
      int c = tid * 4 + c0;
      const f32x4* wr4 = (const f32x4*)(w + (size_t)c * DDIM);
      const f32x4* zr4 = (const f32x4*)zrow;
      f32x4 dv = {0.f, 0.f, 0.f, 0.f};
      for (int q = 0; q < DDIM / 4; ++q) {
        f32x4 a = zr4[q], b = wr4[q];
        dv[0] = fmaf(a[0], b[0], dv[0]); dv[1] = fmaf(a[1], b[1], dv[1]);
        dv[2] = fmaf(a[2], b[2], dv[2]); dv[3] = fmaf(a[3], b[3], dv[3]);
      }
      float s = fmaf(-2.f, (dv[0] + dv[1]) + (dv[2] + dv[3]), wsq[c]);
      if (s < bv) { bv = s; bi = c; }   // c ascending per thread
    }
    rv[tid] = bv; ri[tid] = bi;
    __syncthreads();
    for (int s = 128; s > 0; s >>= 1) {
      if (tid < s) {
        float v2 = rv[tid + s]; int i2 = ri[tid + s];
        if (v2 < rv[tid] || (v2 == rv[tid] && i2 < ri[tid])) { rv[tid] = v2; ri[tid] = i2; }
      }
      __syncthreads();
    }
    const int idx = ri[0];
    if (tid == 0) out[(size_t)IDXOFF + row] = (float)idx;
    float qv = w[(size_t)idx * DDIM + tid];
    float zv = zrow[tid];
    float df = qv - zv;
    out[1 + (size_t)row * DDIM + tid] = zv + df;
    __syncthreads();
    rv[tid] = df * df;
    __syncthreads();
    for (int s = 128; s > 0; s >>= 1) {
      if (tid < s) rv[tid] += rv[tid + s];
      __syncthreads();
    }
    if (tid == 0) atomicAdd(loss_accum, rv[0]);
  }
}

// ---------------- kernel 4: finalize loss ----------------
__global__ void vq_finalize(const float* __restrict__ loss_accum,
                            float* __restrict__ out) {
  out[0] = 0.25f * loss_accum[0] * (1.0f / 16777216.0f);
}

extern "C" void kernel_launch(void* const* d_in, const int* in_sizes, int n_in,
                              void* d_out, int out_size, void* d_ws, size_t ws_size,
                              hipStream_t stream) {
  const float* z = (const float*)d_in[0];
  const float* w = (const float*)d_in[1];
  float* out = (float*)d_out;
  float* wsf = (float*)d_ws;
  float* wsq = wsf + 1024;
  int* cnt = (int*)wsf + 8;
  int* list = (int*)wsf + 2048;

  hipMemsetAsync(d_ws, 0, 64, stream);  // zero loss accum + flag count
  wsq_kernel<<<dim3(KCODES / 256), dim3(256), 0, stream>>>(w, wsq);
  vq_main<<<dim3(NTOT / BRR), dim3(256), 0, stream>>>(z, w, wsq, wsf, cnt, list, out);
  vq_refine<<<dim3(256), dim3(256), 0, stream>>>(z, w, wsq, wsf, cnt, list, out);
  vq_finalize<<<dim3(1), dim3(1), 0, stream>>>(wsf, out);
}

// Round 4
// 374.833 us; speedup vs baseline: 2.4277x; 2.4277x over previous
//
#include <hip/hip_runtime.h>
#include <hip/hip_bf16.h>

typedef float f32x4 __attribute__((ext_vector_type(4)));
typedef short short8 __attribute__((ext_vector_type(8)));

#define NTOT   65536
#define DDIM   256
#define KCODES 1024
#define BRR    128          // z rows per block (vq_main)
#define CT     64           // codes per tile
#define IDXOFF 16777217     // 1 + NTOT*DDIM
#define MARGIN_T4 0.015f    // guard: top-4 spread below this -> full exact rescan

// ws layout (fp32 elems):
//  [0] loss accum | [8] cnt (int) | [16..1040) wsq
//  [2048..264192)   wplanes (64 tiles x 16384 B, swizzled hi|lo images)
//  [264192..526336) cand (65536 x int4)
//  [526336..591872) flags
//  [591872..657408) list (flagged rows)

__device__ __forceinline__ unsigned short bf16_rne(float x) {
  unsigned u = __float_as_uint(x);
  return (unsigned short)((u + 0x7fff + ((u >> 16) & 1)) >> 16);
}

// ---------------- kernel 0: wsq[k] = ||w_k||^2 ----------------
__global__ __launch_bounds__(256) void wsq_kernel(const float* __restrict__ w,
                                                  float* __restrict__ wsq) {
  int k = blockIdx.x * 256 + threadIdx.x;
  if (k >= KCODES) return;
  const f32x4* wr = (const f32x4*)(w + (size_t)k * DDIM);
  float s = 0.f;
#pragma unroll 8
  for (int j = 0; j < DDIM / 4; ++j) {
    f32x4 v = wr[j];
    s += v[0] * v[0] + v[1] * v[1] + v[2] * v[2] + v[3] * v[3];
  }
  wsq[k] = s;
}

// ---------------- kernel 1: w -> hi/lo bf16 planes, tiled+swizzled ----------------
// tile st = ct*4+dc: [64 codes][64 d]; image: hi 8KB | lo 8KB; short at
// byte = row*128 + ((dloc*2) ^ ((row&7)<<4))
__global__ __launch_bounds__(256) void prep_w(const float* __restrict__ w,
                                              float* __restrict__ wplanes) {
  int t = blockIdx.x * 256 + threadIdx.x;  // 65536 = 1024 codes x 64 f32x4 chunks
  int k = t >> 6;
  int d = (t & 63) * 4;
  f32x4 v = *(const f32x4*)(w + (size_t)k * DDIM + d);
  unsigned h[4], l[4];
#pragma unroll
  for (int j = 0; j < 4; ++j) {
    unsigned short hb = bf16_rne(v[j]);
    float hf = __uint_as_float(((unsigned)hb) << 16);
    h[j] = hb;
    l[j] = bf16_rne(v[j] - hf);
  }
  int ct = k >> 6, row = k & 63, dc = d >> 6, dloc = d & 63;
  size_t base = (size_t)(ct * 4 + dc) * 16384;
  int off = row * 128 + ((dloc * 2) ^ ((row & 7) << 4));
  *(int2*)((char*)wplanes + base + off) =
      make_int2((int)(h[0] | (h[1] << 16)), (int)(h[2] | (h[3] << 16)));
  *(int2*)((char*)wplanes + base + 8192 + off) =
      make_int2((int)(l[0] | (l[1] << 16)), (int)(l[2] | (l[3] << 16)));
}

// stage a [128 rows][64 d] fp32 z-chunk as hi/lo bf16 planes (16KB each) into LDS
__device__ __forceinline__ void stage_tile_z(const float* __restrict__ gsrc,
                                             short* hi_t, short* lo_t, int tid) {
#pragma unroll
  for (int it = 0; it < 8; ++it) {
    int flat4 = it * 256 + tid;
    int row = flat4 >> 4;
    int c4 = (flat4 & 15) * 4;
    f32x4 v = *(const f32x4*)(gsrc + (size_t)row * DDIM + c4);
    unsigned h[4], l[4];
#pragma unroll
    for (int j = 0; j < 4; ++j) {
      unsigned short hb = bf16_rne(v[j]);
      float hf = __uint_as_float(((unsigned)hb) << 16);
      h[j] = hb;
      l[j] = bf16_rne(v[j] - hf);
    }
    int off = row * 128 + ((c4 * 2) ^ ((row & 7) << 4));
    *(int2*)((char*)hi_t + off) = make_int2((int)(h[0] | (h[1] << 16)), (int)(h[2] | (h[3] << 16)));
    *(int2*)((char*)lo_t + off) = make_int2((int)(l[0] | (l[1] << 16)), (int)(l[2] | (l[3] << 16)));
  }
}

// async stage one 16KB w tile image: global (pre-swizzled) -> LDS (linear)
__device__ __forceinline__ void stage_w(const float* __restrict__ wpl, int st,
                                        char* buf, int tid) {
  const char* g = (const char*)wpl + (size_t)st * 16384 + tid * 16;
  char* l = buf + ((tid >> 6) << 10);  // wave-uniform base; HW adds lane*16
#pragma unroll
  for (int i = 0; i < 4; ++i)
    __builtin_amdgcn_global_load_lds(
        (const __attribute__((address_space(1))) unsigned int*)(g + i * 4096),
        (__attribute__((address_space(3))) unsigned int*)(l + i * 4096), 16, 0, 0);
}

#define INS4(S0, S1, S2, S3, I0, I1, I2, I3, os, oi)                        \
  if (os < S3 || (os == S3 && oi < I3)) {                                   \
    if (os < S2 || (os == S2 && oi < I2)) {                                 \
      S3 = S2; I3 = I2;                                                     \
      if (os < S1 || (os == S1 && oi < I1)) {                               \
        S2 = S1; I2 = I1;                                                   \
        if (os < S0 || (os == S0 && oi < I0)) {                             \
          S1 = S0; I1 = I0; S0 = os; I0 = oi;                               \
        } else { S1 = os; I1 = oi; }                                        \
      } else { S2 = os; I2 = oi; }                                          \
    } else { S3 = os; I3 = oi; }                                            \
  }

// ---------------- kernel 2: MFMA scores + per-row top-4 candidates ----------------
__global__ __launch_bounds__(256, 2) void vq_main(
    const float* __restrict__ z, const float* __restrict__ wplanes,
    const float* __restrict__ wsq, int* __restrict__ cand,
    int* __restrict__ flags, int* __restrict__ cnt, int* __restrict__ list) {
  __shared__ __align__(16) char lds[36864];  // buf0 16K | buf1 16K | wsq 4K
  float* wsq_l = (float*)(lds + 32768);

  const int tid = threadIdx.x;
  const int lane = tid & 63, wid = tid >> 6;
  const int l15 = lane & 15, lg = lane >> 4;
  const int br = blockIdx.x * BRR;

  for (int i = tid; i < KCODES; i += 256) wsq_l[i] = wsq[i];

  // ---- z fragments -> registers: zf[dc][ks][ni][plane] ----
  short8 zf[4][2][2][2];
  {
    short* zhi = (short*)lds;
    short* zlo = (short*)(lds + 16384);
    const int row0 = wid * 32 + l15, row1 = row0 + 16;
#pragma unroll
    for (int dc = 0; dc < 4; ++dc) {
      __syncthreads();
      stage_tile_z(z + (size_t)br * DDIM + dc * 64, zhi, zlo, tid);
      __syncthreads();
#pragma unroll
      for (int ks = 0; ks < 2; ++ks) {
        const int kb2 = (ks * 32 + lg * 8) * 2;
        const int off0 = row0 * 128 + (kb2 ^ ((row0 & 7) << 4));
        const int off1 = row1 * 128 + (kb2 ^ ((row1 & 7) << 4));
        zf[dc][ks][0][0] = *(const short8*)((char*)zhi + off0);
        zf[dc][ks][0][1] = *(const short8*)((char*)zlo + off0);
        zf[dc][ks][1][0] = *(const short8*)((char*)zhi + off1);
        zf[dc][ks][1][1] = *(const short8*)((char*)zlo + off1);
      }
    }
    __syncthreads();
  }

  // top-4 per z-row (ni=0: row0, ni=1: row1), sorted by (score, idx)
  float a0 = 3.4e38f, a1 = 3.4e38f, a2 = 3.4e38f, a3 = 3.4e38f;
  int e0 = 0x7fffffff, e1 = 0x7fffffff, e2 = 0x7fffffff, e3 = 0x7fffffff;
  float c0 = 3.4e38f, c1 = 3.4e38f, c2 = 3.4e38f, c3 = 3.4e38f;
  int f0 = 0x7fffffff, f1 = 0x7fffffff, f2 = 0x7fffffff, f3 = 0x7fffffff;

  // prologue: stage tile 0
  stage_w(wplanes, 0, lds, tid);
  __syncthreads();

  for (int ct = 0; ct < 16; ++ct) {
    f32x4 acc[4][2];
#pragma unroll
    for (int mi = 0; mi < 4; ++mi)
#pragma unroll
      for (int ni = 0; ni < 2; ++ni) acc[mi][ni] = (f32x4){0.f, 0.f, 0.f, 0.f};

#pragma unroll
    for (int dc = 0; dc < 4; ++dc) {
      const int st = ct * 4 + dc;
      char* cbuf = lds + ((st & 1) << 14);
      char* nbuf = lds + (((st & 1) ^ 1) << 14);
      if (st < 63) stage_w(wplanes, st + 1, nbuf, tid);  // overlaps MFMA below
#pragma unroll
      for (int ks = 0; ks < 2; ++ks) {
#pragma unroll
        for (int mi = 0; mi < 4; ++mi) {
          const int row = mi * 16 + l15;
          const int off = row * 128 + (((ks * 64) + (lg * 16)) ^ ((row & 7) << 4));
          short8 ah = *(const short8*)(cbuf + off);
          short8 al = *(const short8*)(cbuf + 8192 + off);
          acc[mi][0] = __builtin_amdgcn_mfma_f32_16x16x32_bf16(ah, zf[dc][ks][0][0], acc[mi][0], 0, 0, 0);
          acc[mi][0] = __builtin_amdgcn_mfma_f32_16x16x32_bf16(ah, zf[dc][ks][0][1], acc[mi][0], 0, 0, 0);
          acc[mi][0] = __builtin_amdgcn_mfma_f32_16x16x32_bf16(al, zf[dc][ks][0][0], acc[mi][0], 0, 0, 0);
          acc[mi][1] = __builtin_amdgcn_mfma_f32_16x16x32_bf16(ah, zf[dc][ks][1][0], acc[mi][1], 0, 0, 0);
          acc[mi][1] = __builtin_amdgcn_mfma_f32_16x16x32_bf16(ah, zf[dc][ks][1][1], acc[mi][1], 0, 0, 0);
          acc[mi][1] = __builtin_amdgcn_mfma_f32_16x16x32_bf16(al, zf[dc][ks][1][0], acc[mi][1], 0, 0, 0);
        }
      }
      __syncthreads();  // drains stage (vmcnt0) + barrier; cur tile free for overwrite
    }
    // epilogue: scores for this ct, maintain top-4 (codes ascend per lane)
    const int kb = ct * CT;
#pragma unroll
    for (int mi = 0; mi < 4; ++mi)
#pragma unroll
      for (int rg = 0; rg < 4; ++rg) {
        const int cg = kb + mi * 16 + lg * 4 + rg;
        const float w2 = wsq_l[cg];
        float s0v = fmaf(-2.f, acc[mi][0][rg], w2);
        INS4(a0, a1, a2, a3, e0, e1, e2, e3, s0v, cg);
        float s1v = fmaf(-2.f, acc[mi][1][rg], w2);
        INS4(c0, c1, c2, c3, f0, f1, f2, f3, s1v, cg);
      }
  }

  // ---- cross-lane merge of top-4 over the 4 k-groups (xor 16, 32) ----
#pragma unroll
  for (int m = 16; m <= 32; m <<= 1) {
    float os[4]; int oi[4];
    os[0] = __shfl_xor(a0, m); oi[0] = __shfl_xor(e0, m);
    os[1] = __shfl_xor(a1, m); oi[1] = __shfl_xor(e1, m);
    os[2] = __shfl_xor(a2, m); oi[2] = __shfl_xor(e2, m);
    os[3] = __shfl_xor(a3, m); oi[3] = __shfl_xor(e3, m);
#pragma unroll
    for (int t = 0; t < 4; ++t) { INS4(a0, a1, a2, a3, e0, e1, e2, e3, os[t], oi[t]); }
    os[0] = __shfl_xor(c0, m); oi[0] = __shfl_xor(f0, m);
    os[1] = __shfl_xor(c1, m); oi[1] = __shfl_xor(f1, m);
    os[2] = __shfl_xor(c2, m); oi[2] = __shfl_xor(f2, m);
    os[3] = __shfl_xor(c3, m); oi[3] = __shfl_xor(f3, m);
#pragma unroll
    for (int t = 0; t < 4; ++t) { INS4(c0, c1, c2, c3, f0, f1, f2, f3, os[t], oi[t]); }
  }

  if (lg == 0) {
    {
      int grow = br + wid * 32 + l15;
      *(int4*)&cand[(size_t)grow * 4] = make_int4(e0, e1, e2, e3);
      int flg = (a3 - a0 < MARGIN_T4) ? 1 : 0;
      flags[grow] = flg;
      if (flg) { int p = atomicAdd(cnt, 1); list[p] = grow; }
    }
    {
      int grow = br + wid * 32 + 16 + l15;
      *(int4*)&cand[(size_t)grow * 4] = make_int4(f0, f1, f2, f3);
      int flg = (c3 - c0 < MARGIN_T4) ? 1 : 0;
      flags[grow] = flg;
      if (flg) { int p = atomicAdd(cnt, 1); list[p] = grow; }
    }
  }
}

// ---------------- kernel 3: exact fp32 among top-4, gather + loss ----------------
__global__ __launch_bounds__(256) void refine4(
    const float* __restrict__ z, const float* __restrict__ w,
    const float* __restrict__ wsq, const int* __restrict__ cand,
    const int* __restrict__ flags, float* __restrict__ loss_accum,
    float* __restrict__ out) {
  const int tid = threadIdx.x, lane = tid & 63, wv = tid >> 6;
  const int cgrp = lane >> 4, l15 = lane & 15;
  float lsum = 0.f;
  for (int r = blockIdx.x * 4 + wv; r < NTOT; r += gridDim.x * 4) {
    if (flags[r]) continue;  // full-refine owns flagged rows
    const int4 c4 = *(const int4*)&cand[(size_t)r * 4];
    const int myc = (cgrp == 0) ? c4.x : (cgrp == 1) ? c4.y : (cgrp == 2) ? c4.z : c4.w;
    const float* wr = w + (size_t)myc * DDIM;
    const float* zr = z + (size_t)r * DDIM;
    float p = 0.f;
#pragma unroll
    for (int j = 0; j < 4; ++j) {
      f32x4 a = *(const f32x4*)(zr + j * 64 + l15 * 4);
      f32x4 b = *(const f32x4*)(wr + j * 64 + l15 * 4);
      p = fmaf(a[0], b[0], fmaf(a[1], b[1], fmaf(a[2], b[2], fmaf(a[3], b[3], p))));
    }
#pragma unroll
    for (int m = 1; m <= 8; m <<= 1) p += __shfl_xor(p, m);
    float sc = fmaf(-2.f, p, wsq[myc]);
    // all lanes pick best of the 4 exact scores (tie -> lower code idx)
    float bs = __shfl(sc, 0); int bi = c4.x;
    float s1 = __shfl(sc, 16); if (s1 < bs || (s1 == bs && c4.y < bi)) { bs = s1; bi = c4.y; }
    float s2 = __shfl(sc, 32); if (s2 < bs || (s2 == bs && c4.z < bi)) { bs = s2; bi = c4.z; }
    float s3 = __shfl(sc, 48); if (s3 < bs || (s3 == bs && c4.w < bi)) { bs = s3; bi = c4.w; }
    // gather + straight-through write + loss
    f32x4 qv = *(const f32x4*)(w + (size_t)bi * DDIM + lane * 4);
    f32x4 zv = *(const f32x4*)(zr + lane * 4);
    f32x4 o;
#pragma unroll
    for (int j = 0; j < 4; ++j) {
      float df = qv[j] - zv[j];
      o[j] = zv[j] + df;
      lsum = fmaf(df, df, lsum);
    }
    *(f32x4*)(out + 1 + (size_t)r * DDIM + lane * 4) = o;
    if (lane == 0) out[(size_t)IDXOFF + r] = (float)bi;
  }
#pragma unroll
  for (int m = 1; m <= 32; m <<= 1) lsum += __shfl_xor(lsum, m);
  if (lane == 0) atomicAdd(loss_accum, lsum);
}

// ---------------- kernel 4: exact full rescan for flagged rows (expected ~0) ----------------
__global__ __launch_bounds__(256) void vq_refine(
    const float* __restrict__ z, const float* __restrict__ w,
    const float* __restrict__ wsq, float* __restrict__ loss_accum,
    const int* __restrict__ cnt, const int* __restrict__ list,
    float* __restrict__ out) {
  __shared__ __align__(16) float zrow[DDIM];
  __shared__ float rv[256];
  __shared__ int ri[256];
  const int tid = threadIdx.x;
  const int n = *cnt;
  for (int li = blockIdx.x; li < n; li += gridDim.x) {
    const int row = list[li];
    __syncthreads();
    zrow[tid] = z[(size_t)row * DDIM + tid];
    __syncthreads();
    float bv = 3.4e38f; int bi = 0;
#pragma unroll
    for (int c0 = 0; c0 < 4; ++c0) {
      int c = tid * 4 + c0;
      const f32x4* wr4 = (const f32x4*)(w + (size_t)c * DDIM);
      const f32x4* zr4 = (const f32x4*)zrow;
      f32x4 dv = {0.f, 0.f, 0.f, 0.f};
      for (int q = 0; q < DDIM / 4; ++q) {
        f32x4 a = zr4[q], b = wr4[q];
        dv[0] = fmaf(a[0], b[0], dv[0]); dv[1] = fmaf(a[1], b[1], dv[1]);
        dv[2] = fmaf(a[2], b[2], dv[2]); dv[3] = fmaf(a[3], b[3], dv[3]);
      }
      float s = fmaf(-2.f, (dv[0] + dv[1]) + (dv[2] + dv[3]), wsq[c]);
      if (s < bv) { bv = s; bi = c; }
    }
    rv[tid] = bv; ri[tid] = bi;
    __syncthreads();
    for (int s = 128; s > 0; s >>= 1) {
      if (tid < s) {
        float v2 = rv[tid + s]; int i2 = ri[tid + s];
        if (v2 < rv[tid] || (v2 == rv[tid] && i2 < ri[tid])) { rv[tid] = v2; ri[tid] = i2; }
      }
      __syncthreads();
    }
    const int idx = ri[0];
    if (tid == 0) out[(size_t)IDXOFF + row] = (float)idx;
    float qv = w[(size_t)idx * DDIM + tid];
    float zv = zrow[tid];
    float df = qv - zv;
    out[1 + (size_t)row * DDIM + tid] = zv + df;
    __syncthreads();
    rv[tid] = df * df;
    __syncthreads();
    for (int s = 128; s > 0; s >>= 1) {
      if (tid < s) rv[tid] += rv[tid + s];
      __syncthreads();
    }
    if (tid == 0) atomicAdd(loss_accum, rv[0]);
  }
}

// ---------------- kernel 5: finalize loss ----------------
__global__ void vq_finalize(const float* __restrict__ loss_accum,
                            float* __restrict__ out) {
  out[0] = 0.25f * loss_accum[0] * (1.0f / 16777216.0f);
}

extern "C" void kernel_launch(void* const* d_in, const int* in_sizes, int n_in,
                              void* d_out, int out_size, void* d_ws, size_t ws_size,
                              hipStream_t stream) {
  const float* z = (const float*)d_in[0];
  const float* w = (const float*)d_in[1];
  float* out = (float*)d_out;
  float* wsf = (float*)d_ws;
  float* wsq = wsf + 16;
  float* wplanes = wsf + 2048;
  int* cand = (int*)(wsf + 264192);
  int* flags = (int*)(wsf + 526336);
  int* list = (int*)(wsf + 591872);
  int* cnt = (int*)wsf + 8;

  hipMemsetAsync(d_ws, 0, 64, stream);  // loss accum + cnt
  wsq_kernel<<<dim3(KCODES / 256), dim3(256), 0, stream>>>(w, wsq);
  prep_w<<<dim3(256), dim3(256), 0, stream>>>(w, wplanes);
  vq_main<<<dim3(NTOT / BRR), dim3(256), 0, stream>>>(z, wplanes, wsq, cand, flags, cnt, list);
  refine4<<<dim3(1024), dim3(256), 0, stream>>>(z, w, wsq, cand, flags, wsf, out);
  vq_refine<<<dim3(128), dim3(256), 0, stream>>>(z, w, wsq, wsf, cnt, list, out);
  vq_finalize<<<dim3(1), dim3(1), 0, stream>>>(wsf, out);
}

// Round 5
// 309.254 us; speedup vs baseline: 2.9425x; 1.2121x over previous
//
#include <hip/hip_runtime.h>
#include <hip/hip_bf16.h>

typedef float f32x4 __attribute__((ext_vector_type(4)));
typedef short short8 __attribute__((ext_vector_type(8)));

#define NTOT   65536
#define DDIM   256
#define KCODES 1024
#define BRR    128          // z rows per block (vq_main)
#define CT     64           // codes per tile
#define IDXOFF 16777217     // 1 + NTOT*DDIM
#define MARGIN_T4 0.015f    // guard: top-4 spread below this -> full exact rescan

// ws layout (fp32 elems):
//  [0..64)   loss buckets | ((int*)ws)[64] cnt | [80..1104) wsq
//  [2048..264192)   wplanes (64 tiles x 16KB, swizzled hi|lo images)
//  [264192..526336) cand (65536 x int4)
//  [526336..591872) flags
//  [591872..657408) list (flagged rows)

__device__ __forceinline__ unsigned short bf16_rne(float x) {
  unsigned u = __float_as_uint(x);
  return (unsigned short)((u + 0x7fff + ((u >> 16) & 1)) >> 16);
}

// ---------------- kernel 0: wsq[k] = ||w_k||^2 ----------------
__global__ __launch_bounds__(256) void wsq_kernel(const float* __restrict__ w,
                                                  float* __restrict__ wsq) {
  int k = blockIdx.x * 256 + threadIdx.x;
  if (k >= KCODES) return;
  const f32x4* wr = (const f32x4*)(w + (size_t)k * DDIM);
  float s = 0.f;
#pragma unroll 8
  for (int j = 0; j < DDIM / 4; ++j) {
    f32x4 v = wr[j];
    s += v[0] * v[0] + v[1] * v[1] + v[2] * v[2] + v[3] * v[3];
  }
  wsq[k] = s;
}

// ---------------- kernel 1: w -> hi/lo bf16 planes, tiled+swizzled ----------------
__global__ __launch_bounds__(256) void prep_w(const float* __restrict__ w,
                                              float* __restrict__ wplanes) {
  int t = blockIdx.x * 256 + threadIdx.x;
  int k = t >> 6;
  int d = (t & 63) * 4;
  f32x4 v = *(const f32x4*)(w + (size_t)k * DDIM + d);
  unsigned h[4], l[4];
#pragma unroll
  for (int j = 0; j < 4; ++j) {
    unsigned short hb = bf16_rne(v[j]);
    float hf = __uint_as_float(((unsigned)hb) << 16);
    h[j] = hb;
    l[j] = bf16_rne(v[j] - hf);
  }
  int ct = k >> 6, row = k & 63, dc = d >> 6, dloc = d & 63;
  size_t base = (size_t)(ct * 4 + dc) * 16384;
  int off = row * 128 + ((dloc * 2) ^ ((row & 7) << 4));
  *(int2*)((char*)wplanes + base + off) =
      make_int2((int)(h[0] | (h[1] << 16)), (int)(h[2] | (h[3] << 16)));
  *(int2*)((char*)wplanes + base + 8192 + off) =
      make_int2((int)(l[0] | (l[1] << 16)), (int)(l[2] | (l[3] << 16)));
}

// stage a [128 rows][64 d] fp32 z-chunk as hi/lo bf16 planes into LDS
__device__ __forceinline__ void stage_tile_z(const float* __restrict__ gsrc,
                                             short* hi_t, short* lo_t, int tid) {
#pragma unroll
  for (int it = 0; it < 8; ++it) {
    int flat4 = it * 256 + tid;
    int row = flat4 >> 4;
    int c4 = (flat4 & 15) * 4;
    f32x4 v = *(const f32x4*)(gsrc + (size_t)row * DDIM + c4);
    unsigned h[4], l[4];
#pragma unroll
    for (int j = 0; j < 4; ++j) {
      unsigned short hb = bf16_rne(v[j]);
      float hf = __uint_as_float(((unsigned)hb) << 16);
      h[j] = hb;
      l[j] = bf16_rne(v[j] - hf);
    }
    int off = row * 128 + ((c4 * 2) ^ ((row & 7) << 4));
    *(int2*)((char*)hi_t + off) = make_int2((int)(h[0] | (h[1] << 16)), (int)(h[2] | (h[3] << 16)));
    *(int2*)((char*)lo_t + off) = make_int2((int)(l[0] | (l[1] << 16)), (int)(l[2] | (l[3] << 16)));
  }
}

// async stage one 32KB pair of w tiles: pre-swizzled global -> linear LDS
__device__ __forceinline__ void stage_w2(const float* __restrict__ wpl, int pr,
                                         char* buf, int tid) {
  const char* g = (const char*)wpl + (size_t)pr * 32768 + tid * 16;
  char* l = buf + ((tid >> 6) << 10);  // wave-uniform base; HW adds lane*16
#pragma unroll
  for (int i = 0; i < 8; ++i)
    __builtin_amdgcn_global_load_lds(
        (const __attribute__((address_space(1))) unsigned int*)(g + i * 4096),
        (__attribute__((address_space(3))) unsigned int*)(l + i * 4096), 16, 0, 0);
}

#define INS4(S0, S1, S2, S3, I0, I1, I2, I3, os, oi)                        \
  if (os < S3 || (os == S3 && oi < I3)) {                                   \
    if (os < S2 || (os == S2 && oi < I2)) {                                 \
      S3 = S2; I3 = I2;                                                     \
      if (os < S1 || (os == S1 && oi < I1)) {                               \
        S2 = S1; I2 = I1;                                                   \
        if (os < S0 || (os == S0 && oi < I0)) {                             \
          S1 = S0; I1 = I0; S0 = os; I0 = oi;                               \
        } else { S1 = os; I1 = oi; }                                        \
      } else { S2 = os; I2 = oi; }                                          \
    } else { S3 = os; I3 = oi; }                                            \
  }

#define MFMA_STEP(DC, TB)                                                   \
  {                                                                         \
    _Pragma("unroll")                                                       \
    for (int ks = 0; ks < 2; ++ks) {                                        \
      _Pragma("unroll")                                                     \
      for (int mi = 0; mi < 4; ++mi) {                                      \
        const int row = mi * 16 + l15;                                      \
        const int off = row * 128 + (((ks * 64) + (lg * 16)) ^ ((row & 7) << 4)); \
        short8 ah = *(const short8*)((TB) + off);                           \
        short8 al = *(const short8*)((TB) + 8192 + off);                    \
        acc[mi][0] = __builtin_amdgcn_mfma_f32_16x16x32_bf16(ah, zf[DC][ks][0][0], acc[mi][0], 0, 0, 0); \
        acc[mi][0] = __builtin_amdgcn_mfma_f32_16x16x32_bf16(ah, zf[DC][ks][0][1], acc[mi][0], 0, 0, 0); \
        acc[mi][0] = __builtin_amdgcn_mfma_f32_16x16x32_bf16(al, zf[DC][ks][0][0], acc[mi][0], 0, 0, 0); \
        acc[mi][1] = __builtin_amdgcn_mfma_f32_16x16x32_bf16(ah, zf[DC][ks][1][0], acc[mi][1], 0, 0, 0); \
        acc[mi][1] = __builtin_amdgcn_mfma_f32_16x16x32_bf16(ah, zf[DC][ks][1][1], acc[mi][1], 0, 0, 0); \
        acc[mi][1] = __builtin_amdgcn_mfma_f32_16x16x32_bf16(al, zf[DC][ks][1][0], acc[mi][1], 0, 0, 0); \
      }                                                                     \
    }                                                                       \
  }

// ---------------- kernel 2: MFMA scores + per-row top-4 candidates ----------------
__global__ __launch_bounds__(256, 2) void vq_main(
    const float* __restrict__ z, const float* __restrict__ wplanes,
    const float* __restrict__ wsq, int* __restrict__ cand,
    int* __restrict__ flags, int* __restrict__ cnt, int* __restrict__ list) {
  __shared__ __align__(16) char lds[69632];  // buf0 32K | buf1 32K | wsq 4K
  char* buf0 = lds;
  char* buf1 = lds + 32768;
  float* wsq_l = (float*)(lds + 65536);

  const int tid = threadIdx.x;
  const int lane = tid & 63, wid = tid >> 6;
  const int l15 = lane & 15, lg = lane >> 4;
  const int br = blockIdx.x * BRR;

  for (int i = tid; i < KCODES; i += 256) wsq_l[i] = wsq[i];

  // ---- z fragments -> registers: zf[dc][ks][ni][plane] ----
  short8 zf[4][2][2][2];
  {
    short* zhi = (short*)lds;
    short* zlo = (short*)(lds + 16384);
    const int row0 = wid * 32 + l15, row1 = row0 + 16;
#pragma unroll
    for (int dc = 0; dc < 4; ++dc) {
      __syncthreads();
      stage_tile_z(z + (size_t)br * DDIM + dc * 64, zhi, zlo, tid);
      __syncthreads();
#pragma unroll
      for (int ks = 0; ks < 2; ++ks) {
        const int kb2 = (ks * 32 + lg * 8) * 2;
        const int off0 = row0 * 128 + (kb2 ^ ((row0 & 7) << 4));
        const int off1 = row1 * 128 + (kb2 ^ ((row1 & 7) << 4));
        zf[dc][ks][0][0] = *(const short8*)((char*)zhi + off0);
        zf[dc][ks][0][1] = *(const short8*)((char*)zlo + off0);
        zf[dc][ks][1][0] = *(const short8*)((char*)zhi + off1);
        zf[dc][ks][1][1] = *(const short8*)((char*)zlo + off1);
      }
    }
    __syncthreads();
  }

  // top-4 per z-row, sorted by (score, idx)
  float a0 = 3.4e38f, a1 = 3.4e38f, a2 = 3.4e38f, a3 = 3.4e38f;
  int e0 = 0x7fffffff, e1 = 0x7fffffff, e2 = 0x7fffffff, e3 = 0x7fffffff;
  float c0 = 3.4e38f, c1 = 3.4e38f, c2 = 3.4e38f, c3 = 3.4e38f;
  int f0 = 0x7fffffff, f1 = 0x7fffffff, f2 = 0x7fffffff, f3 = 0x7fffffff;

  // prologue: stage pair 0 (tiles 0,1) into buf0
  stage_w2(wplanes, 0, buf0, tid);
  __syncthreads();

  for (int ct = 0; ct < 16; ++ct) {
    f32x4 acc[4][2];
#pragma unroll
    for (int mi = 0; mi < 4; ++mi)
#pragma unroll
      for (int ni = 0; ni < 2; ++ni) acc[mi][ni] = (f32x4){0.f, 0.f, 0.f, 0.f};

    // even step: compute pair 2ct (dc 0,1) in buf0; prefetch pair 2ct+1 -> buf1
    stage_w2(wplanes, ct * 2 + 1, buf1, tid);
    MFMA_STEP(0, buf0)
    MFMA_STEP(1, buf0 + 16384)
    __syncthreads();
    // odd step: compute pair 2ct+1 (dc 2,3) in buf1; prefetch pair 2ct+2 -> buf0
    if (ct < 15) stage_w2(wplanes, ct * 2 + 2, buf0, tid);
    MFMA_STEP(2, buf1)
    MFMA_STEP(3, buf1 + 16384)
    __syncthreads();

    // epilogue: guarded top-4 insertion (most scores fail the a3 test -> ~3 cyc)
    const int kb = ct * CT;
#pragma unroll
    for (int mi = 0; mi < 4; ++mi)
#pragma unroll
      for (int rg = 0; rg < 4; ++rg) {
        const int cg = kb + mi * 16 + lg * 4 + rg;
        const float w2 = wsq_l[cg];
        float s0v = fmaf(-2.f, acc[mi][0][rg], w2);
        if (s0v < a3 || (s0v == a3 && cg < e3)) { INS4(a0, a1, a2, a3, e0, e1, e2, e3, s0v, cg); }
        float s1v = fmaf(-2.f, acc[mi][1][rg], w2);
        if (s1v < c3 || (s1v == c3 && cg < f3)) { INS4(c0, c1, c2, c3, f0, f1, f2, f3, s1v, cg); }
      }
  }

  // ---- cross-lane merge of top-4 over the 4 k-groups (xor 16, 32) ----
#pragma unroll
  for (int m = 16; m <= 32; m <<= 1) {
    float os[4]; int oi[4];
    os[0] = __shfl_xor(a0, m); oi[0] = __shfl_xor(e0, m);
    os[1] = __shfl_xor(a1, m); oi[1] = __shfl_xor(e1, m);
    os[2] = __shfl_xor(a2, m); oi[2] = __shfl_xor(e2, m);
    os[3] = __shfl_xor(a3, m); oi[3] = __shfl_xor(e3, m);
#pragma unroll
    for (int t = 0; t < 4; ++t) { INS4(a0, a1, a2, a3, e0, e1, e2, e3, os[t], oi[t]); }
    os[0] = __shfl_xor(c0, m); oi[0] = __shfl_xor(f0, m);
    os[1] = __shfl_xor(c1, m); oi[1] = __shfl_xor(f1, m);
    os[2] = __shfl_xor(c2, m); oi[2] = __shfl_xor(f2, m);
    os[3] = __shfl_xor(c3, m); oi[3] = __shfl_xor(f3, m);
#pragma unroll
    for (int t = 0; t < 4; ++t) { INS4(c0, c1, c2, c3, f0, f1, f2, f3, os[t], oi[t]); }
  }

  if (lg == 0) {
    {
      int grow = br + wid * 32 + l15;
      *(int4*)&cand[(size_t)grow * 4] = make_int4(e0, e1, e2, e3);
      int flg = (a3 - a0 < MARGIN_T4) ? 1 : 0;
      flags[grow] = flg;
      if (flg) { int p = atomicAdd(cnt, 1); list[p] = grow; }
    }
    {
      int grow = br + wid * 32 + 16 + l15;
      *(int4*)&cand[(size_t)grow * 4] = make_int4(f0, f1, f2, f3);
      int flg = (c3 - c0 < MARGIN_T4) ? 1 : 0;
      flags[grow] = flg;
      if (flg) { int p = atomicAdd(cnt, 1); list[p] = grow; }
    }
  }
}

// ---------------- kernel 3: fused exact top-4 pick + gather + write + loss ----------------
__global__ __launch_bounds__(256) void refine_fused(
    const float* __restrict__ z, const float* __restrict__ w,
    const float* __restrict__ wsq, const int* __restrict__ cand,
    const int* __restrict__ flags, float* __restrict__ buckets,
    float* __restrict__ out) {
  __shared__ float ws4[4];
  const int tid = threadIdx.x, lane = tid & 63, wv = tid >> 6;
  float lsum = 0.f;
  for (int r = blockIdx.x * 4 + wv; r < NTOT; r += gridDim.x * 4) {
    if (flags[r]) continue;  // full-rescan kernel owns flagged rows
    const int4 c4 = *(const int4*)&cand[(size_t)r * 4];
    f32x4 zv = *(const f32x4*)(z + (size_t)r * DDIM + lane * 4);
    f32x4 w0 = *(const f32x4*)(w + (size_t)c4.x * DDIM + lane * 4);
    f32x4 w1 = *(const f32x4*)(w + (size_t)c4.y * DDIM + lane * 4);
    f32x4 w2 = *(const f32x4*)(w + (size_t)c4.z * DDIM + lane * 4);
    f32x4 w3 = *(const f32x4*)(w + (size_t)c4.w * DDIM + lane * 4);
    float p0 = fmaf(zv[0], w0[0], fmaf(zv[1], w0[1], fmaf(zv[2], w0[2], zv[3] * w0[3])));
    float p1 = fmaf(zv[0], w1[0], fmaf(zv[1], w1[1], fmaf(zv[2], w1[2], zv[3] * w1[3])));
    float p2 = fmaf(zv[0], w2[0], fmaf(zv[1], w2[1], fmaf(zv[2], w2[2], zv[3] * w2[3])));
    float p3 = fmaf(zv[0], w3[0], fmaf(zv[1], w3[1], fmaf(zv[2], w3[2], zv[3] * w3[3])));
#pragma unroll
    for (int m = 1; m <= 32; m <<= 1) {
      p0 += __shfl_xor(p0, m);
      p1 += __shfl_xor(p1, m);
      p2 += __shfl_xor(p2, m);
      p3 += __shfl_xor(p3, m);
    }
    float s0 = fmaf(-2.f, p0, wsq[c4.x]);
    float s1 = fmaf(-2.f, p1, wsq[c4.y]);
    float s2 = fmaf(-2.f, p2, wsq[c4.z]);
    float s3 = fmaf(-2.f, p3, wsq[c4.w]);
    float bs = s0; int bi = c4.x;
    if (s1 < bs || (s1 == bs && c4.y < bi)) { bs = s1; bi = c4.y; }
    if (s2 < bs || (s2 == bs && c4.z < bi)) { bs = s2; bi = c4.z; }
    if (s3 < bs || (s3 == bs && c4.w < bi)) { bs = s3; bi = c4.w; }
    f32x4 qv = *(const f32x4*)(w + (size_t)bi * DDIM + lane * 4);
    f32x4 o;
#pragma unroll
    for (int j = 0; j < 4; ++j) {
      float df = qv[j] - zv[j];
      o[j] = zv[j] + df;
      lsum = fmaf(df, df, lsum);
    }
    *(f32x4*)(out + 1 + (size_t)r * DDIM + lane * 4) = o;
    if (lane == 0) out[(size_t)IDXOFF + r] = (float)bi;
  }
#pragma unroll
  for (int m = 1; m <= 32; m <<= 1) lsum += __shfl_xor(lsum, m);
  if (lane == 0) ws4[wv] = lsum;
  __syncthreads();
  if (tid == 0)
    atomicAdd(&buckets[blockIdx.x & 63], ws4[0] + ws4[1] + ws4[2] + ws4[3]);
}

// ---------------- kernel 4: exact full rescan for flagged rows (expected ~0) ----------------
__global__ __launch_bounds__(256) void vq_refine(
    const float* __restrict__ z, const float* __restrict__ w,
    const float* __restrict__ wsq, float* __restrict__ buckets,
    const int* __restrict__ cnt, const int* __restrict__ list,
    float* __restrict__ out) {
  __shared__ __align__(16) float zrow[DDIM];
  __shared__ float rv[256];
  __shared__ int ri[256];
  const int tid = threadIdx.x;
  const int n = *cnt;
  for (int li = blockIdx.x; li < n; li += gridDim.x) {
    const int row = list[li];
    __syncthreads();
    zrow[tid] = z[(size_t)row * DDIM + tid];
    __syncthreads();
    float bv = 3.4e38f; int bi = 0;
#pragma unroll
    for (int c0 = 0; c0 < 4; ++c0) {
      int c = tid * 4 + c0;
      const f32x4* wr4 = (const f32x4*)(w + (size_t)c * DDIM);
      const f32x4* zr4 = (const f32x4*)zrow;
      f32x4 dv = {0.f, 0.f, 0.f, 0.f};
      for (int q = 0; q < DDIM / 4; ++q) {
        f32x4 a = zr4[q], b = wr4[q];
        dv[0] = fmaf(a[0], b[0], dv[0]); dv[1] = fmaf(a[1], b[1], dv[1]);
        dv[2] = fmaf(a[2], b[2], dv[2]); dv[3] = fmaf(a[3], b[3], dv[3]);
      }
      float s = fmaf(-2.f, (dv[0] + dv[1]) + (dv[2] + dv[3]), wsq[c]);
      if (s < bv) { bv = s; bi = c; }
    }
    rv[tid] = bv; ri[tid] = bi;
    __syncthreads();
    for (int s = 128; s > 0; s >>= 1) {
      if (tid < s) {
        float v2 = rv[tid + s]; int i2 = ri[tid + s];
        if (v2 < rv[tid] || (v2 == rv[tid] && i2 < ri[tid])) { rv[tid] = v2; ri[tid] = i2; }
      }
      __syncthreads();
    }
    const int idx = ri[0];
    if (tid == 0) out[(size_t)IDXOFF + row] = (float)idx;
    float qv = w[(size_t)idx * DDIM + tid];
    float zv = zrow[tid];
    float df = qv - zv;
    out[1 + (size_t)row * DDIM + tid] = zv + df;
    __syncthreads();
    rv[tid] = df * df;
    __syncthreads();
    for (int s = 128; s > 0; s >>= 1) {
      if (tid < s) rv[tid] += rv[tid + s];
      __syncthreads();
    }
    if (tid == 0) atomicAdd(&buckets[0], rv[0]);
  }
}

// ---------------- kernel 5: finalize loss ----------------
__global__ void vq_finalize(const float* __restrict__ buckets,
                            float* __restrict__ out) {
  float s = 0.f;
  for (int i = 0; i < 64; ++i) s += buckets[i];
  out[0] = 0.25f * s * (1.0f / 16777216.0f);
}

extern "C" void kernel_launch(void* const* d_in, const int* in_sizes, int n_in,
                              void* d_out, int out_size, void* d_ws, size_t ws_size,
                              hipStream_t stream) {
  const float* z = (const float*)d_in[0];
  const float* w = (const float*)d_in[1];
  float* out = (float*)d_out;
  float* wsf = (float*)d_ws;
  float* buckets = wsf;
  int* cnt = (int*)wsf + 64;
  float* wsq = wsf + 80;
  float* wplanes = wsf + 2048;
  int* cand = (int*)(wsf + 264192);
  int* flags = (int*)(wsf + 526336);
  int* list = (int*)(wsf + 591872);

  hipMemsetAsync(d_ws, 0, 320, stream);  // buckets + cnt
  wsq_kernel<<<dim3(KCODES / 256), dim3(256), 0, stream>>>(w, wsq);
  prep_w<<<dim3(256), dim3(256), 0, stream>>>(w, wplanes);
  vq_main<<<dim3(NTOT / BRR), dim3(256), 0, stream>>>(z, wplanes, wsq, cand, flags, cnt, list);
  refine_fused<<<dim3(4096), dim3(256), 0, stream>>>(z, w, wsq, cand, flags, buckets, out);
  vq_refine<<<dim3(128), dim3(256), 0, stream>>>(z, w, wsq, buckets, cnt, list, out);
  vq_finalize<<<dim3(1), dim3(1), 0, stream>>>(buckets, out);
}